// Round 1
// baseline (70.118 us; speedup 1.0000x reference)
//
#include <hip/hip_runtime.h>

#define IN_C 64
#define OUT_C 64
#define HW 32
#define PH 34  // padded 32+2

// ---- pad x: [2][64][32][32] -> [2][64][34][34] with zero border ----
__global__ void pad_kernel(const float* __restrict__ x, float* __restrict__ xp) {
    int i = blockIdx.x * blockDim.x + threadIdx.x;
    const int total = 2 * IN_C * PH * PH;
    if (i >= total) return;
    int col = i % PH;
    int row = (i / PH) % PH;
    int bc  = i / (PH * PH);
    float v = 0.0f;
    if (row >= 1 && row <= HW && col >= 1 && col <= HW)
        v = x[bc * HW * HW + (row - 1) * HW + (col - 1)];
    xp[i] = v;
}

// ---- transpose weight: w[o][ckk] -> wt[ckk][o], ckk in [0,576) ----
__global__ void wtr_kernel(const float* __restrict__ w, float* __restrict__ wt) {
    int i = blockIdx.x * blockDim.x + threadIdx.x;  // i = ckk*64 + o
    const int total = 576 * 64;
    if (i >= total) return;
    int o = i & 63;
    int ckk = i >> 6;
    wt[i] = w[o * 576 + ckk];
}

// ---- main: y[b][o][oh][ow] = (sum_{c,kh,kw} (xpad - w)^8)^(1/8) + bias[o] ----
// grid 512 = b(2) * og(16) * tile(16); block 256 = cs(4) * sp(64)
// wave = 64 spatial positions (coalesced x); cs (c-quarter) wave-uniform;
// og (4 consecutive out-channels) block-uniform -> weight loads are uniform.
__global__ __launch_bounds__(256, 2) void norm_conv_kernel(
    const float* __restrict__ xp, const float* __restrict__ wt,
    const float* __restrict__ bias, float* __restrict__ out) {
    int bid = blockIdx.x;
    int tile = bid & 15;
    int og = (bid >> 4) & 15;
    int b = bid >> 8;

    int tid = threadIdx.x;
    int sp = tid & 63;
    int cs = __builtin_amdgcn_readfirstlane(tid >> 6);  // wave-uniform c-quarter
    int row = sp >> 5, col = sp & 31;
    int oh = tile * 2 + row;
    int ow = col;

    const float* xb = xp + ((size_t)(b * IN_C + cs * 16) * PH + oh) * PH + ow;
    const float* wb = wt + (size_t)(cs * 16) * 9 * 64 + og * 4;

    float s0 = 0.f, s1 = 0.f, s2 = 0.f, s3 = 0.f;

    for (int c = 0; c < 16; ++c) {
        const float* xr = xb + c * (PH * PH);
        const float* wr = wb + c * (9 * 64);
#pragma unroll
        for (int kh = 0; kh < 3; ++kh) {
#pragma unroll
            for (int kw = 0; kw < 3; ++kw) {
                float xv = xr[kh * PH + kw];
                float4 wv = *(const float4*)(wr + (kh * 3 + kw) * 64);
                float d0 = xv - wv.x;
                float d1 = xv - wv.y;
                float d2 = xv - wv.z;
                float d3 = xv - wv.w;
                d0 *= d0; d0 *= d0; s0 = fmaf(d0, d0, s0);
                d1 *= d1; d1 *= d1; s1 = fmaf(d1, d1, s1);
                d2 *= d2; d2 *= d2; s2 = fmaf(d2, d2, s2);
                d3 *= d3; d3 *= d3; s3 = fmaf(d3, d3, s3);
            }
        }
    }

    // combine the 4 c-split partials via LDS
    __shared__ float lds[4 * 64 * 4];  // [cs][sp][oi]
    ((float4*)lds)[tid] = make_float4(s0, s1, s2, s3);
    __syncthreads();

    int oi = tid >> 6;      // which of the 4 output channels
    int sp2 = tid & 63;     // spatial position
    float sum = lds[(0 * 64 + sp2) * 4 + oi] + lds[(1 * 64 + sp2) * 4 + oi] +
                lds[(2 * 64 + sp2) * 4 + oi] + lds[(3 * 64 + sp2) * 4 + oi];

    float y = exp2f(0.125f * log2f(sum));  // sum^(1/8); sum>0 always here
    int o = og * 4 + oi;
    int oh2 = tile * 2 + (sp2 >> 5);
    int ow2 = sp2 & 31;
    out[((b * OUT_C + o) * HW + oh2) * HW + ow2] = y + bias[o];
}

extern "C" void kernel_launch(void* const* d_in, const int* in_sizes, int n_in,
                              void* d_out, int out_size, void* d_ws, size_t ws_size,
                              hipStream_t stream) {
    const float* x = (const float*)d_in[0];      // [2,64,32,32]
    const float* w = (const float*)d_in[1];      // [64,64,3,3]
    const float* bias = (const float*)d_in[2];   // [64]
    float* out = (float*)d_out;                  // [2,64,32,32]

    float* xp = (float*)d_ws;                          // 2*64*34*34 floats
    float* wt = xp + 2 * IN_C * PH * PH;               // 576*64 floats

    {
        int total = 2 * IN_C * PH * PH;
        pad_kernel<<<(total + 255) / 256, 256, 0, stream>>>(x, xp);
    }
    {
        int total = 576 * 64;
        wtr_kernel<<<(total + 255) / 256, 256, 0, stream>>>(w, wt);
    }
    norm_conv_kernel<<<512, 256, 0, stream>>>(xp, wt, bias, out);
}